// Round 5
// baseline (104.296 us; speedup 1.0000x reference)
//
#include <hip/hip_runtime.h>
#include <cstdint>
#include <cstddef>

typedef __attribute__((ext_vector_type(4))) float f32x4;
typedef __attribute__((ext_vector_type(8))) short bf16x8;
typedef __attribute__((ext_vector_type(4))) short bf16x4;
typedef __attribute__((ext_vector_type(2))) short bf16x2;

#define DEVI static __device__ __forceinline__

DEVI short f2bf(float f){
  union { float f; uint32_t u; } v; v.f = f;
  uint32_t r = v.u + 0x7FFFu + ((v.u >> 16) & 1u);
  return (short)(r >> 16);
}
DEVI float bf2f(short h){
  union { uint32_t u; float f; } v; v.u = ((uint32_t)(uint16_t)h) << 16;
  return v.f;
}
DEVI float eluf(float x){ return x > 0.f ? x : (__expf(x) - 1.f); }
DEVI float sigm(float x){ return 1.f / (1.f + __expf(-x)); }

DEVI void gload16(const void* g, void* l){
  __builtin_amdgcn_global_load_lds((const __attribute__((address_space(1))) void*)g,
                                   (__attribute__((address_space(3))) void*)l, 16, 0, 0);
}

static constexpr int NPIX = 8 * 1024;   // B*S pixels

// ---- workspace layout (bytes) ----
static constexpr size_t SZ_W   = (size_t)983040 * 2;        // 3 x 40 stages x 32 rows x 256 k (pre-swizzled bf16)
static constexpr size_t SZ_ACT = (size_t)NPIX * 256 * 2;
static constexpr size_t OFF_W   = 0;
static constexpr size_t OFF_TOK = OFF_W + SZ_W + 8*SZ_ACT;  // 3 x (B,512,1024) bf16 flat

// ---------------- weight prep: fp32 -> bf16, stage-major, PRE-SWIZZLED ----------------
// Output layout per branch z: 40 stages x 32 rows x 32 slots x 8 shorts, where
// dst[stage][r][s_][e] = Worig[row(stage,r)][ (s_ ^ (r&7))*8 + e ].
// k_branch stages this linearly via global_load_lds; MFMA reads apply the same XOR.
// Stage map: 0-7 = W1 rows s*32.. ; 8-23 = W2 (t=s-8): rows (t&2)<<7 | (t>>2)<<6 | (t&1)<<5 ;
// 24-39 = Wn rows (s-24)*32.
__global__ void k_prep(const float* __restrict__ w1q, const float* __restrict__ w2q, const float* __restrict__ wnq,
                       const float* __restrict__ w1k, const float* __restrict__ w2k, const float* __restrict__ wnk,
                       const float* __restrict__ w1v, const float* __restrict__ w2v, const float* __restrict__ wnv,
                       short* __restrict__ dst)
{
  const float* s1[3] = {w1q, w1k, w1v};
  const float* s2[3] = {w2q, w2k, w2v};
  const float* s3[3] = {wnq, wnk, wnv};
  int u = blockIdx.x * 256 + threadIdx.x;          // one 16B unit per thread
  if (u >= 122880) return;
  int z = u / 40960, rem = u % 40960;
  int stage = rem >> 10, rem2 = rem & 1023;
  int r = rem2 >> 5, s_ = rem2 & 31;
  int cslot = s_ ^ (r & 7);
  const float* src; int row;
  if (stage < 8){ src = s1[z]; row = stage*32 + r; }
  else if (stage < 24){ int t = stage - 8; src = s2[z]; row = ((t&2)<<7) + ((t>>2)<<6) + ((t&1)<<5) + r; }
  else { src = s3[z]; row = (stage-24)*32 + r; }
  const float* p = src + (size_t)row*256 + cslot*8;
  short* dq = dst + (size_t)u*8;
  #pragma unroll
  for (int e = 0; e < 8; e++) dq[e] = f2bf(p[e]);
}

// ---------------- fused branch kernel, v3 ----------------
// One block = 128 tokens x one branch z; 4 waves, each wave owns 32 tokens
// (2 x 16-token groups) end-to-end. B-operands live in registers; h1/gr
// round-trip through WAVE-PRIVATE LDS (no barriers). W is staged block-wide
// via global_load_lds from the pre-swizzled stage stream: double-buffered,
// 40 stages, ONE barrier per stage, next stage's loads issued at stage top
// (a full stage of MFMA+ds_read covers the L2 latency).
// LDS = 2x16KB (W dbuf) + 4x16KB (h1/gr) = 96 KB -> 1 block/CU; grid 192.
__global__ __launch_bounds__(256, 1)
void k_branch(const short* __restrict__ wsW,
              const float* __restrict__ query, const float* __restrict__ key,
              const float* __restrict__ b1q, const float* __restrict__ b1k, const float* __restrict__ b1v,
              const float* __restrict__ b2q, const float* __restrict__ b2k, const float* __restrict__ b2v,
              const float* __restrict__ bnq, const float* __restrict__ bnk, const float* __restrict__ bnv,
              short* __restrict__ tok)
{
  __shared__ short sW[2][8192];    // 2 x (32 rows x 256 k), pre-swizzled
  __shared__ short sHG[4][8192];   // per-wave 32 tokens x 256 (h1, then gr overlay)

  const int z = blockIdx.y;
  const float* xin = (z == 0) ? query : key;
  const float* b1z = (z == 0) ? b1q : ((z == 1) ? b1k : b1v);
  const float* b2z = (z == 0) ? b2q : ((z == 1) ? b2k : b2v);
  const float* bnz = (z == 0) ? bnq : ((z == 1) ? bnk : bnv);
  const short* Wz = wsW + (size_t)z * 327680;
  short* tokz = tok + (size_t)z * NPIX * 512;

  const int tid = threadIdx.x, w = tid >> 6, lane = tid & 63, g = (tid >> 4) & 3, li = tid & 15;
  const int gtok = blockIdx.x * 128;
  const int b = gtok >> 10;
  const int sb = (gtok & 1023) + w*32;     // wave's token base
  short* sHw = &sHG[w][0];
  const float* xb = xin + (size_t)b * 256 * 1024;

  // stage s -> buffer nb (pure linear copy; 4 x 1KB per wave)
#define STAGE(S, NB)                                                            \
  { const char* gs_ = (const char*)(Wz + (size_t)(S)*8192) + w*4096 + lane*16;  \
    char* ls_ = (char*)&sW[(NB)][0] + w*4096;                                   \
    gload16(gs_,        ls_);                                                   \
    gload16(gs_ + 1024, ls_ + 1024);                                            \
    gload16(gs_ + 2048, ls_ + 2048);                                            \
    gload16(gs_ + 3072, ls_ + 3072); }

  // prologue: stage 0 into buf 0, then B-fragments (covers the load latency)
  STAGE(0, 0);

  // GEMM1 B: elu(x), transpose-free: lane (g,li) holds ex[k=ks*32+g*8+j][tok sb+th*16+li]
  bf16x8 bB[2][8];
  #pragma unroll
  for (int th = 0; th < 2; th++)
    #pragma unroll
    for (int ks = 0; ks < 8; ks++)
      #pragma unroll
      for (int j = 0; j < 8; j++){
        float e = xb[(size_t)(ks*32 + g*8 + j)*1024 + sb + th*16 + li];
        bB[th][ks][j] = f2bf(eluf(e));
      }
  __syncthreads();

  // ---- GEMM1: h1 = elu(W1 @ ex + b1) -> sHw[token][m] (8 stages) ----
  for (int s = 0; s < 8; s++){
    STAGE(s + 1, (s + 1) & 1);
    const short* bufc = &sW[s & 1][0];
    f32x4 acc[2][2] = {};
    #pragma unroll
    for (int ks = 0; ks < 8; ks++)
      #pragma unroll
      for (int mt = 0; mt < 2; mt++){
        bf16x8 afr = *(const bf16x8*)(bufc + (mt*16 + li)*256 + (((ks*4 + g) ^ (li & 7)) << 3));
        #pragma unroll
        for (int th = 0; th < 2; th++)
          acc[th][mt] = __builtin_amdgcn_mfma_f32_16x16x32_bf16(afr, bB[th][ks], acc[th][mt], 0, 0, 0);
      }
    #pragma unroll
    for (int th = 0; th < 2; th++)
      #pragma unroll
      for (int mt = 0; mt < 2; mt++){
        int m0 = s*32 + mt*16 + g*4;
        bf16x4 pk;
        #pragma unroll
        for (int r = 0; r < 4; r++)
          pk[r] = f2bf(eluf(acc[th][mt][r] + b1z[m0 + r]));
        *(bf16x4*)(sHw + (th*16 + li)*256 + (m0 ^ ((li & 7) << 3))) = pk;
      }
    __syncthreads();
  }

  // hoist h1 into registers (wave-private)
  bf16x8 bH[2][8];
  #pragma unroll
  for (int th = 0; th < 2; th++)
    #pragma unroll
    for (int ks = 0; ks < 8; ks++)
      bH[th][ks] = *(const bf16x8*)(sHw + (th*16 + li)*256 + (((ks*4 + g) ^ (li & 7)) << 3));

  // ---- GEMM2: [a;g] = W2 @ h1 + b2 ; gr = x + a*sig(g) -> sHw overlay (16 stages) ----
  for (int mp = 0; mp < 4; mp++){
    f32x4 acc2[2][8] = {};
    #pragma unroll
    for (int q = 0; q < 4; q++){
      const int s = 8 + mp*4 + q;
      STAGE(s + 1, (s + 1) & 1);
      const short* bufc = &sW[s & 1][0];
      #pragma unroll
      for (int ks = 0; ks < 8; ks++)
        #pragma unroll
        for (int mt = 0; mt < 2; mt++){
          bf16x8 afr = *(const bf16x8*)(bufc + (mt*16 + li)*256 + (((ks*4 + g) ^ (li & 7)) << 3));
          #pragma unroll
          for (int th = 0; th < 2; th++)
            acc2[th][q*2 + mt] = __builtin_amdgcn_mfma_f32_16x16x32_bf16(afr, bH[th][ks], acc2[th][q*2 + mt], 0, 0, 0);
        }
      __syncthreads();
    }
    // epilogue: q∈{0,1} = a-half, q∈{2,3} = g-half (acc slot +4), rows mp*64+q*32+mt*16
    #pragma unroll
    for (int th = 0; th < 2; th++)
      #pragma unroll
      for (int q = 0; q < 2; q++)
        #pragma unroll
        for (int mt = 0; mt < 2; mt++){
          int m0 = mp*64 + q*32 + mt*16 + g*4;
          bf16x4 pk;
          #pragma unroll
          for (int r = 0; r < 4; r++){
            float a  = acc2[th][q*2 + mt][r] + b2z[m0 + r];
            float gg = acc2[th][q*2 + mt + 4][r] + b2z[m0 + r + 256];
            float xv = xb[(size_t)(m0 + r)*1024 + sb + th*16 + li];
            pk[r] = f2bf(xv + a * sigm(gg));
          }
          *(bf16x4*)(sHw + (th*16 + li)*256 + (m0 ^ ((li & 7) << 3))) = pk;
        }
  }

  // hoist gr into registers
  bf16x8 bG[2][8];
  #pragma unroll
  for (int th = 0; th < 2; th++)
    #pragma unroll
    for (int ks = 0; ks < 8; ks++)
      bG[th][ks] = *(const bf16x8*)(sHw + (th*16 + li)*256 + (((ks*4 + g) ^ (li & 7)) << 3));

  // ---- GEMM3: tok = Wn @ gr + bn -> global flat [b][512][1024] bf16 (16 stages) ----
  for (int s3 = 0; s3 < 16; s3++){
    const int s = 24 + s3;
    if (s + 1 < 40) STAGE(s + 1, (s + 1) & 1);
    const short* bufc = &sW[s & 1][0];
    f32x4 acc[2][2] = {};
    #pragma unroll
    for (int ks = 0; ks < 8; ks++)
      #pragma unroll
      for (int mt = 0; mt < 2; mt++){
        bf16x8 afr = *(const bf16x8*)(bufc + (mt*16 + li)*256 + (((ks*4 + g) ^ (li & 7)) << 3));
        #pragma unroll
        for (int th = 0; th < 2; th++)
          acc[th][mt] = __builtin_amdgcn_mfma_f32_16x16x32_bf16(afr, bG[th][ks], acc[th][mt], 0, 0, 0);
      }
    #pragma unroll
    for (int th = 0; th < 2; th++)
      #pragma unroll
      for (int mt = 0; mt < 2; mt++)
        #pragma unroll
        for (int r = 0; r < 4; r++){
          int m = s3*32 + mt*16 + g*4 + r;
          tokz[((size_t)b*512 + m)*1024 + sb + th*16 + li] = f2bf(acc[th][mt][r] + bnz[m]);
        }
    if (s + 1 < 40) __syncthreads();
  }
#undef STAGE
}

// ---------------- flash attention ----------------
// tok viewed as (B*1024 tokens, 512 feat) bf16; per (b, head): Q,K,V (1024 x 64).
// Strict causal (key < query), scale 1/sqrt(512), row 0 -> 0.
// Swapped QK^T: S^T = mfma(K, Q^T) so softmax state is lane-local.
// Grid = 1024 flat blocks; qt permuted so every stride-256 block family (one CU
// under XCD round-robin) has equal total work (perm stride-4 subsets sum to 30).
__global__ void k_attn(const short* __restrict__ tok, float* __restrict__ out)
{
  const short* qtok = tok;
  const short* ktok = tok + (size_t)NPIX * 512;
  const short* vtok = tok + (size_t)2 * NPIX * 512;
  const int flat = blockIdx.x;
  const int p = flat >> 6;
  const int g4 = p >> 2, r4 = p & 3;
  // perm = [15,14,13,12, 0,1,2,3, 11,10,9,8, 4,5,6,7]
  const int qt = (g4 == 0) ? (15 - r4) : (g4 == 1) ? r4 : (g4 == 2) ? (11 - r4) : (4 + r4);
  const int bh = flat & 63;
  const int b = bh >> 3, nh = bh & 7;
  const int tid = threadIdx.x, lane = tid & 63, w = tid >> 6, g = (tid >> 4) & 3, li = tid & 15;
  const int qrow = qt*64 + w*16 + li;       // this lane's query token
  __shared__ short Kl[64*64];
  __shared__ short Vt[64*64];               // V transposed: [d][k]
  __shared__ short Pl[4][1024];             // per-wave P [16 q][64 k]

  const short* qptr = qtok + ((size_t)(b*1024 + qrow))*512 + nh*64;
  bf16x8 qf0 = *(const bf16x8*)(qptr + g*8);
  bf16x8 qf1 = *(const bf16x8*)(qptr + 32 + g*8);

  f32x4 accO[4] = {};                       // O^T: 4 d-frags x (16d x 16q)
  float mrun = -1e30f, lrun = 0.f;
  const float scale = 0.04419417382415922f; // 1/sqrt(512)
  short* Pw = &Pl[w][0];

  for (int kt = 0; kt <= qt; kt++){
    const int kb = kt * 64;
    __syncthreads();
    #pragma unroll
    for (int it = 0; it < 2; it++){
      int i = tid + it*256;
      int kr = i >> 3, kc = i & 7;
      bf16x8 v = *(const bf16x8*)(ktok + ((size_t)(b*1024 + kb + kr))*512 + nh*64 + kc*8);
      *(bf16x8*)(Kl + ((kr*64 + kc*8) ^ ((kr & 7) << 3))) = v;
    }
    #pragma unroll
    for (int it = 0; it < 2; it++){
      int d0 = w*8 + it*32;                 // d uniform within wave -> conflict-free writes
      bf16x8 v = *(const bf16x8*)(vtok + ((size_t)(b*1024 + kb + lane))*512 + nh*64 + d0);
      #pragma unroll
      for (int j = 0; j < 8; j++){
        int d = d0 + j;
        Vt[(d*64 + lane) ^ ((d & 7) << 3)] = v[j];
      }
    }
    __syncthreads();

    // S^T frags: 4 x (16 keys x 16 q)
    float pv[16];
    float mt_ = -1e30f;
    const bool diag = (kt == qt);
    #pragma unroll
    for (int kf = 0; kf < 4; kf++){
      f32x4 sa = {};
      const int krow = kf*16 + li;
      bf16x8 ka  = *(const bf16x8*)(Kl + ((krow*64 + g*8) ^ ((krow & 7) << 3)));
      bf16x8 kbf = *(const bf16x8*)(Kl + ((krow*64 + 32 + g*8) ^ ((krow & 7) << 3)));
      sa = __builtin_amdgcn_mfma_f32_16x16x32_bf16(ka, qf0, sa, 0, 0, 0);
      sa = __builtin_amdgcn_mfma_f32_16x16x32_bf16(kbf, qf1, sa, 0, 0, 0);
      #pragma unroll
      for (int r = 0; r < 4; r++){
        const int keyg = kb + kf*16 + g*4 + r;
        float s = sa[r] * scale;
        const bool ok = (!diag) || (keyg < qrow);   // strict causal
        s = ok ? s : -1e30f;
        pv[kf*4 + r] = s;
        mt_ = fmaxf(mt_, s);
      }
    }
    mt_ = fmaxf(mt_, __shfl_xor(mt_, 16));
    mt_ = fmaxf(mt_, __shfl_xor(mt_, 32));
    const float mnew = fmaxf(mrun, mt_);
    const float alpha = __expf(mrun - mnew);
    short pr[16];
    float rs = 0.f;
    #pragma unroll
    for (int i2 = 0; i2 < 16; i2++){
      float p2 = (pv[i2] > -9e29f) ? __expf(pv[i2] - mnew) : 0.f;
      short pb = f2bf(p2);
      pr[i2] = pb;
      rs += bf2f(pb);            // denominator from rounded P (consistent with numerator)
    }
    rs += __shfl_xor(rs, 16);
    rs += __shfl_xor(rs, 32);
    lrun = lrun * alpha + rs;
    mrun = mnew;
    #pragma unroll
    for (int df = 0; df < 4; df++){
      accO[df][0] *= alpha; accO[df][1] *= alpha;
      accO[df][2] *= alpha; accO[df][3] *= alpha;
    }
    // P rows to per-wave LDS (b32 packed pairs; keys 4g+2rp consecutive)
    #pragma unroll
    for (int kf = 0; kf < 4; kf++){
      #pragma unroll
      for (int rp = 0; rp < 2; rp++){
        bf16x2 two;
        two[0] = pr[kf*4 + rp*2];
        two[1] = pr[kf*4 + rp*2 + 1];
        const int key = kf*16 + g*4 + rp*2;
        *(bf16x2*)(Pw + ((li*64 + key) ^ ((li & 7) << 3))) = two;
      }
    }
    // O^T += V^T @ P^T
    #pragma unroll
    for (int kc = 0; kc < 2; kc++){
      bf16x8 pf = *(const bf16x8*)(Pw + ((li*64 + kc*32 + g*8) ^ ((li & 7) << 3)));
      #pragma unroll
      for (int df = 0; df < 4; df++){
        const int dr = df*16 + li;
        bf16x8 vf = *(const bf16x8*)(Vt + ((dr*64 + kc*32 + g*8) ^ ((dr & 7) << 3)));
        accO[df] = __builtin_amdgcn_mfma_f32_16x16x32_bf16(vf, pf, accO[df], 0, 0, 0);
      }
    }
  }
  const float inv = (lrun > 0.f) ? (1.f / lrun) : 0.f;  // row 0: lrun==0 -> zeros (start_mask)
  #pragma unroll
  for (int df = 0; df < 4; df++){
    #pragma unroll
    for (int r = 0; r < 4; r++){
      const int d = df*16 + g*4 + r;
      out[((size_t)b*512 + nh*64 + d)*1024 + qrow] = accO[df][r] * inv;
    }
  }
}

extern "C" void kernel_launch(void* const* d_in, const int* in_sizes, int n_in,
                              void* d_out, int out_size, void* d_ws, size_t ws_size,
                              hipStream_t stream)
{
  (void)in_sizes; (void)n_in; (void)out_size; (void)ws_size;
  const float* query = (const float*)d_in[0];
  const float* key   = (const float*)d_in[1];
  const float* w1[3] = {(const float*)d_in[2],  (const float*)d_in[8],  (const float*)d_in[14]};
  const float* b1[3] = {(const float*)d_in[3],  (const float*)d_in[9],  (const float*)d_in[15]};
  const float* w2[3] = {(const float*)d_in[4],  (const float*)d_in[10], (const float*)d_in[16]};
  const float* b2[3] = {(const float*)d_in[5],  (const float*)d_in[11], (const float*)d_in[17]};
  const float* wn[3] = {(const float*)d_in[6],  (const float*)d_in[12], (const float*)d_in[18]};
  const float* bn[3] = {(const float*)d_in[7],  (const float*)d_in[13], (const float*)d_in[19]};

  char* ws = (char*)d_ws;
  short* wsW = (short*)(ws + OFF_W);
  short* tok = (short*)(ws + OFF_TOK);
  float* out = (float*)d_out;

  k_prep<<<dim3(480), dim3(256), 0, stream>>>(w1[0], w2[0], wn[0],
                                              w1[1], w2[1], wn[1],
                                              w1[2], w2[2], wn[2], wsW);
  k_branch<<<dim3(64, 3), dim3(256), 0, stream>>>(wsW, query, key,
                                                  b1[0], b1[1], b1[2],
                                                  b2[0], b2[1], b2[2],
                                                  bn[0], bn[1], bn[2], tok);
  k_attn<<<dim3(1024), dim3(256), 0, stream>>>(tok, out);
}